// Round 11
// baseline (100.321 us; speedup 1.0000x reference)
//
#include <hip/hip_runtime.h>

typedef short short8 __attribute__((ext_vector_type(8)));
typedef float floatx4 __attribute__((ext_vector_type(4)));

#define B_    4
#define NPTS  8192          // N == M == 8192
#define IS    16            // i-splits (512 src per block)
#define JS    32            // j-splits (256 dst per block)
#define ITB   512
#define JTB   256
#define NT    8             // i-tiles per wave (16 i each -> 128 i/wave)
#define NJT   16            // j-tiles per block
#define TOT   (B_ * NPTS)   // 32768

// LDS offsets in short8 units (typed => 16B-aligned). A=dst (256 pts),
// B=src (512 pts); seg0/seg1 = k0..7 / k8..15. Z: zero block for quads 2,3.
#define A0OFF 0
#define A1OFF 260
#define B0OFF 524
#define B1OFF 1040
#define ZOFF  1556
#define LDS8N 1557          // 24,912 B -> 6 blocks/CU (R9's 33 KB capped at 4)

// ws: slots uint32[2*TOT] = 256 KiB, memset 0xFF. Monotone float->uint map.

__device__ __forceinline__ unsigned short bf16h(float v) {
  unsigned u = __float_as_uint(v);
  return (unsigned short)((u + 0x7FFFu + ((u >> 16) & 1u)) >> 16);   // RNE
}
__device__ __forceinline__ void bf16split(float v, unsigned short& h, unsigned short& l) {
  h = bf16h(v);
  l = bf16h(v - __uint_as_float((unsigned)h << 16));
}

// K-slot scheme (k0..15 real, k16..31 zero) — R9-verified (absmax 0.0):
//   A (dst j): k0..7  [axh axh axl axl  ayh ayh ayl ayl]      a = -2g
//              k8..15 [azh azh azl azl  wh  wl  1   1 ]       w = ||g||^2
//   B (src i): k0..7  [pxh pxl pxh pxl  pyh pyl pyh pyl]
//              k8..15 [pzh pzl pzh pzl  1   1   qh  ql]       q = ||p||^2
__device__ __forceinline__ void pack_dst(const float* g, short8& s0, short8& s1) {
  const float x = g[0], y = g[1], z = g[2];
  const float w = fmaf(x, x, fmaf(y, y, z * z));
  unsigned short xh, xl, yh, yl, zh, zl, wh, wl;
  bf16split(-2.f * x, xh, xl); bf16split(-2.f * y, yh, yl);
  bf16split(-2.f * z, zh, zl); bf16split(w, wh, wl);
  s0 = (short8){(short)xh,(short)xh,(short)xl,(short)xl,
                (short)yh,(short)yh,(short)yl,(short)yl};
  s1 = (short8){(short)zh,(short)zh,(short)zl,(short)zl,
                (short)wh,(short)wl,(short)0x3F80,(short)0x3F80};
}
__device__ __forceinline__ void pack_src(const float* p, short8& s0, short8& s1) {
  const float x = p[0], y = p[1], z = p[2];
  const float qq = fmaf(x, x, fmaf(y, y, z * z));
  unsigned short xh, xl, yh, yl, zh, zl, qh, ql;
  bf16split(x, xh, xl); bf16split(y, yh, yl);
  bf16split(z, zh, zl); bf16split(qq, qh, ql);
  s0 = (short8){(short)xh,(short)xl,(short)xh,(short)xl,
                (short)yh,(short)yl,(short)yh,(short)yl};
  s1 = (short8){(short)zh,(short)zl,(short)zh,(short)zl,
                (short)0x3F80,(short)0x3F80,(short)qh,(short)ql};
}

// grid (IS, JS, 2*B_) = (16,32,8) = 4096 blocks, 256 thr (4 waves).
// Block: 512 i x 256 j. Wave w: i in [w*128, w*128+128), all 256 j.
// R9-exact fragment handling (16x16x32, quads 2-3 on zero block) +
// register prefetch of af across jt (R9's exposed ds_read latency).
__global__ __launch_bounds__(256, 6) void mfma_pass_kernel(
    const float* __restrict__ pred, const float* __restrict__ gt,
    unsigned* __restrict__ slots) {
  __shared__ short8 lds8[LDS8N];

  const int zb  = blockIdx.z;
  const int dir = zb >> 2;
  const int b   = zb & 3;
  const float* src = dir ? gt   : pred;   // i-cloud (min FOR these)
  const float* dst = dir ? pred : gt;     // j-cloud (min OVER these)

  const int tid   = threadIdx.x;
  const int lane  = tid & 63;
  const int w     = tid >> 6;
  const int jbase = blockIdx.y * JTB;
  const int ibase = blockIdx.x * ITB;

  if (tid == 0) lds8[ZOFF] = (short8)0;

  // Stage: 256 dst (1/thread) + 512 src (2/thread).
  {
    short8 s0, s1;
    pack_dst(dst + ((size_t)b * NPTS + jbase + tid) * 3, s0, s1);
    lds8[A0OFF + tid] = s0;
    lds8[A1OFF + tid] = s1;
#pragma unroll
    for (int r = 0; r < 2; ++r) {
      const int pt = tid + r * 256;
      pack_src(src + ((size_t)b * NPTS + ibase + pt) * 3, s0, s1);
      lds8[B0OFF + pt] = s0;
      lds8[B1OFF + pt] = s1;
    }
  }
  __syncthreads();

  const int  q  = lane >> 4;     // quad: holds k = q*8..q*8+7
  const int  n  = lane & 15;     // point index within tile (A: j, B: i)
  const bool kq = (q < 2);       // quads 0,1 real k; 2,3 zeros

  short8 bf[NT];
  float  m[NT];
  const int bseg = kq ? (q ? B1OFF : B0OFF) : ZOFF;
#pragma unroll
  for (int t = 0; t < NT; ++t) {
    bf[t] = lds8[bseg + (kq ? (w * 128 + t * 16 + n) : 0)];
    m[t] = 1e30f;
  }

  const int aseg  = kq ? (q ? A1OFF : A0OFF) : ZOFF;
  const int abase = aseg + (kq ? n : 0);
  const int astep = kq ? 16 : 0;   // quads 2,3 stay pinned on the zero block

  const floatx4 zero4 = {0.f, 0.f, 0.f, 0.f};
  short8 af = lds8[abase];                    // jt = 0
  for (int jt = 0; jt < NJT; ++jt) {
    const int jn = (jt + 1 < NJT) ? (jt + 1) : 0;
    const short8 afn = lds8[abase + jn * astep];   // prefetch next j-tile
#pragma unroll
    for (int t = 0; t < NT; ++t) {
      // D[j][i]: lane = col i=n, rows j = 4q..4q+3 (C/D layout m89/m91).
      floatx4 d = __builtin_amdgcn_mfma_f32_16x16x32_bf16(af, bf[t], zero4, 0, 0, 0);
      m[t] = fminf(m[t], fminf(fminf(d[0], d[1]), fminf(d[2], d[3])));
    }
    af = afn;
  }

  // Cross-quad min (lanes n, n+16, n+32, n+48 share col i=n), then ONE
  // atomicMin per (i, block).
#pragma unroll
  for (int t = 0; t < NT; ++t) {
    float v = m[t];
    v = fminf(v, __shfl_xor(v, 16));
    v = fminf(v, __shfl_xor(v, 32));
    if (lane < 16) {
      const int gi = ibase + w * 128 + t * 16 + lane;
      const int bi = __float_as_int(v);
      const unsigned u = (unsigned)bi ^ (unsigned)((bi >> 31) | 0x80000000);
      atomicMin(&slots[(size_t)(dir * B_ + b) * NPTS + gi], u);
    }
  }
}

// Sweep 2*TOT slots, decode, reduce, one atomic per block.  (R5-proven)
__global__ __launch_bounds__(256) void pass2_kernel(
    const unsigned* __restrict__ slots, float* __restrict__ out) {
  const int gid = blockIdx.x * 256 + threadIdx.x;   // 8192 threads
  float s = 0.f;
#pragma unroll
  for (int k = 0; k < 8; ++k) {
    const unsigned u = slots[gid + k * 8192];
    const int bi = (u & 0x80000000u) ? (int)(u ^ 0x80000000u) : (int)~u;
    s += __int_as_float(bi);
  }
  __shared__ float red[256];
  const int tid = threadIdx.x;
  red[tid] = s;
  __syncthreads();
  for (int st = 128; st > 0; st >>= 1) {
    if (tid < st) red[tid] += red[tid + st];
    __syncthreads();
  }
  if (tid == 0) atomicAdd(out, red[0] * (1.0f / TOT));
}

extern "C" void kernel_launch(void* const* d_in, const int* in_sizes, int n_in,
                              void* d_out, int out_size, void* d_ws, size_t ws_size,
                              hipStream_t stream) {
  const float* pred = (const float*)d_in[0];
  const float* gt   = (const float*)d_in[1];
  unsigned* slots = (unsigned*)d_ws;
  float* out = (float*)d_out;

  hipMemsetAsync(slots, 0xFF, (size_t)2 * TOT * sizeof(unsigned), stream);
  hipMemsetAsync(out, 0, out_size * sizeof(float), stream);

  dim3 g(IS, JS, 2 * B_);   // 4096 blocks
  mfma_pass_kernel<<<g, 256, 0, stream>>>(pred, gt, slots);

  pass2_kernel<<<(2 * TOT) / (256 * 8), 256, 0, stream>>>(slots, out);
}